// Round 8
// baseline (258.884 us; speedup 1.0000x reference)
//
#include <hip/hip_runtime.h>
#include <stdint.h>

typedef uint16_t u16;
typedef uint32_t u32;
typedef __bf16 bf16;
typedef bf16 bf16x8 __attribute__((ext_vector_type(8)));
typedef bf16 bf16x4 __attribute__((ext_vector_type(4)));
typedef float f32x4 __attribute__((ext_vector_type(4)));
typedef u16 u16x4 __attribute__((ext_vector_type(4)));

#define MFMA(a, b, c) __builtin_amdgcn_mfma_f32_16x16x32_bf16((a), (b), (c), 0, 0, 0)

#define BATCH 8
#define SEQ 1024
#define DMODEL 1024
#define NH 16
#define DK 64
#define LOG2E 1.4426950408889634f

// HW bf16 convert (RNE): gfx950 selects v_cvt_pk_bf16_f32 for fptrunc
__device__ __forceinline__ u16 bfbits(float f) {
    bf16 h = (bf16)f;
    return __builtin_bit_cast(u16, h);
}

// raw v_exp_f32 (args bounded |x|<~45 here; skip libm's range-guard sequence)
__device__ __forceinline__ float exp2_raw(float x) {
    float r;
    asm("v_exp_f32 %0, %1" : "=v"(r) : "v"(x));
    return r;
}

// async global->LDS, 16B per lane; LDS dst = wave-uniform base + lane*16
__device__ __forceinline__ void gload_lds16(const u16* g, u16* l) {
    __builtin_amdgcn_global_load_lds(
        (__attribute__((address_space(1))) void*)g,
        (__attribute__((address_space(3))) void*)l, 16, 0, 0);
}

// ---------------- merged prep: x->bf16, W->bf16^T, F4 bias table ----------------
// blocks [0,8192): convert x; [8192,9216): transpose-convert weights (64x64 tiles);
// [9216,9344): F4 bias. Branch is block-uniform; __syncthreads only in wt branch.
__global__ __launch_bounds__(256) void prep_kernel(
        const float* __restrict__ x, const float* __restrict__ W0,
        const float* __restrict__ W1, const float* __restrict__ W2,
        const float* __restrict__ W3, const float* __restrict__ rel_emb,
        u16* __restrict__ xb, u16* __restrict__ T0, u16* __restrict__ T1,
        u16* __restrict__ T2, u16* __restrict__ T3, f32x4* __restrict__ F4) {
    __shared__ u16 Ts[64 * 72];        // wt branch only
    const int bid = blockIdx.x, tid = threadIdx.x;
    if (bid < 8192) {
        size_t id = (size_t)bid * 256 + tid;
        f32x4 v = *(const f32x4*)(x + id * 4);
        bf16x4 o;
        o[0] = (bf16)v[0]; o[1] = (bf16)v[1]; o[2] = (bf16)v[2]; o[3] = (bf16)v[3];
        *(bf16x4*)(xb + id * 4) = o;
    } else if (bid < 9216) {
        const int t = bid - 8192;
        const int z = t >> 8, rem = t & 255;
        const float* W = (z == 0) ? W0 : (z == 1) ? W1 : (z == 2) ? W2 : W3;
        u16* T = (z == 0) ? T0 : (z == 1) ? T1 : (z == 2) ? T2 : T3;
        const int k0 = (rem >> 4) * 64, n0 = (rem & 15) * 64;
        const int r16 = tid >> 4, c0 = (tid & 15) * 4;
        #pragma unroll
        for (int rr = 0; rr < 4; rr++) {
            int r = rr * 16 + r16;     // k-row within tile
            f32x4 vv = *(const f32x4*)&W[(size_t)(k0 + r) * 1024 + n0 + c0];
            #pragma unroll
            for (int i = 0; i < 4; i++) Ts[(c0 + i) * 72 + r] = bfbits(vv[i]);
        }
        __syncthreads();
        int n = tid >> 2, seg = (tid & 3) * 16;
        *(bf16x8*)&T[(size_t)(n0 + n) * 1024 + k0 + seg] = *(const bf16x8*)&Ts[n * 72 + seg];
        *(bf16x8*)&T[(size_t)(n0 + n) * 1024 + k0 + seg + 8] =
            *(const bf16x8*)&Ts[n * 72 + seg + 8];
    } else {
        int id = (bid - 9216) * 256 + tid;
        if (id >= NH * 2047) return;
        int h = id / 2047, tt0 = id % 2047;
        f32x4 o;
        #pragma unroll
        for (int j = 0; j < 4; j++) {
            int tt = tt0 + j;
            float val = 0.f;
            if (tt <= 2046) {
                int rel = tt - 1023;
                int n = -rel;
                int b = 0;
                if (n < 0) { b = 16; n = -n; }
                int v;
                if (n < 8) {
                    v = n;
                } else {
                    int e = 31 - __clz(n);
                    int f = 2 * e + ((unsigned)(n * n) >= (1u << (2 * e + 1)) ? 1 : 0);
                    v = min(2 + f, 15);
                }
                val = LOG2E * rel_emb[(b + v) * NH + h];
            }
            o[j] = val;
        }
        F4[(size_t)h * 2047 + tt0] = o;
    }
}

// ---------------- QKV projection GEMM (R6 BK=32 body — proven best) ----------------
// grid: x = m0 (64) -> per-XCD A-tile L2 residency; y = n0 + 8*z (24).
__global__ __launch_bounds__(256) void gemm_qkv_kernel(
        const u16* __restrict__ xb,
        const u16* __restrict__ Wqt, const u16* __restrict__ Wkt, const u16* __restrict__ Wvt,
        u16* __restrict__ qb, u16* __restrict__ kb, u16* __restrict__ vb) {
    __shared__ u16 As[128 * 32];   // unpadded: required by global_load_lds lane layout
    __shared__ u16 Bs[128 * 32];
    const int z = blockIdx.y >> 3;
    const u16* Bt = (z == 0) ? Wqt : (z == 1) ? Wkt : Wvt;
    const int m0 = blockIdx.x * 128, n0 = (blockIdx.y & 7) * 128;
    const int tid = threadIdx.x, w = tid >> 6, lane = tid & 63;
    const int quad = lane >> 4, l16 = lane & 15;
    const int rw = w >> 1, cw = w & 1;
    const int srow = lane >> 2, sseg = lane & 3;   // lane covers row w*16+srow, 16B seg

    f32x4 acc[4][4];
    #pragma unroll
    for (int i = 0; i < 4; i++)
        #pragma unroll
        for (int j = 0; j < 4; j++) acc[i][j] = (f32x4){0.f, 0.f, 0.f, 0.f};

    for (int kk = 0; kk < 1024; kk += 32) {
        __syncthreads();
        #pragma unroll
        for (int r = 0; r < 2; r++) {
            int base = r * 64 + w * 16;
            int row = base + srow;
            gload_lds16(&xb[(size_t)(m0 + row) * 1024 + kk + sseg * 8], &As[base * 32]);
            gload_lds16(&Bt[(size_t)(n0 + row) * 1024 + kk + sseg * 8], &Bs[base * 32]);
        }
        __syncthreads();
        bf16x8 af[4], bfr[4];
        #pragma unroll
        for (int mt = 0; mt < 4; mt++)
            af[mt] = *(const bf16x8*)&As[(rw * 64 + mt * 16 + l16) * 32 + quad * 8];
        #pragma unroll
        for (int nt = 0; nt < 4; nt++)
            bfr[nt] = *(const bf16x8*)&Bs[(cw * 64 + nt * 16 + l16) * 32 + quad * 8];
        #pragma unroll
        for (int mt = 0; mt < 4; mt++)
            #pragma unroll
            for (int nt = 0; nt < 4; nt++)
                acc[mt][nt] = MFMA(af[mt], bfr[nt], acc[mt][nt]);
    }

    #pragma unroll
    for (int mt = 0; mt < 4; mt++) {
        int gmBase = m0 + rw * 64 + mt * 16 + quad * 4;
        #pragma unroll
        for (int nt = 0; nt < 4; nt++) {
            int gn = n0 + cw * 64 + nt * 16 + l16;
            int h = gn >> 6, dk = gn & 63;
            if (z == 2) {
                // V^T store: s = gmBase..+3 consecutive -> one u16x4
                int b_ = gmBase >> 10, s0 = gmBase & 1023;
                u16x4 pk = { bfbits(acc[mt][nt][0]), bfbits(acc[mt][nt][1]),
                             bfbits(acc[mt][nt][2]), bfbits(acc[mt][nt][3]) };
                *(u16x4*)&vb[(((size_t)b_ * NH + h) * DK + dk) * SEQ + s0] = pk;
            } else {
                u16* o = z ? kb : qb;
                #pragma unroll
                for (int r = 0; r < 4; r++) {
                    int gm = gmBase + r;
                    int b_ = gm >> 10, s = gm & 1023;
                    float sv = acc[mt][nt][r];
                    if (z == 0) sv *= LOG2E;       // fold exp2 scale into Q
                    o[(((size_t)b_ * NH + h) * SEQ + s) * DK + dk] = bfbits(sv);
                }
            }
        }
    }
}

// ---------------- output projection GEMM (R6 BK=32 body, fp32 out) ----------------
__global__ __launch_bounds__(256) void gemm_out_kernel(
        const u16* __restrict__ ctx, const u16* __restrict__ Wot, float* __restrict__ out) {
    __shared__ u16 As[128 * 32];
    __shared__ u16 Bs[128 * 32];
    const int m0 = blockIdx.x * 128, n0 = blockIdx.y * 128;
    const int tid = threadIdx.x, w = tid >> 6, lane = tid & 63;
    const int quad = lane >> 4, l16 = lane & 15;
    const int rw = w >> 1, cw = w & 1;
    const int srow = lane >> 2, sseg = lane & 3;

    f32x4 acc[4][4];
    #pragma unroll
    for (int i = 0; i < 4; i++)
        #pragma unroll
        for (int j = 0; j < 4; j++) acc[i][j] = (f32x4){0.f, 0.f, 0.f, 0.f};

    for (int kk = 0; kk < 1024; kk += 32) {
        __syncthreads();
        #pragma unroll
        for (int r = 0; r < 2; r++) {
            int base = r * 64 + w * 16;
            int row = base + srow;
            gload_lds16(&ctx[(size_t)(m0 + row) * 1024 + kk + sseg * 8], &As[base * 32]);
            gload_lds16(&Wot[(size_t)(n0 + row) * 1024 + kk + sseg * 8], &Bs[base * 32]);
        }
        __syncthreads();
        bf16x8 af[4], bfr[4];
        #pragma unroll
        for (int mt = 0; mt < 4; mt++)
            af[mt] = *(const bf16x8*)&As[(rw * 64 + mt * 16 + l16) * 32 + quad * 8];
        #pragma unroll
        for (int nt = 0; nt < 4; nt++)
            bfr[nt] = *(const bf16x8*)&Bs[(cw * 64 + nt * 16 + l16) * 32 + quad * 8];
        #pragma unroll
        for (int mt = 0; mt < 4; mt++)
            #pragma unroll
            for (int nt = 0; nt < 4; nt++)
                acc[mt][nt] = MFMA(af[mt], bfr[nt], acc[mt][nt]);
    }

    #pragma unroll
    for (int mt = 0; mt < 4; mt++) {
        int gmBase = m0 + rw * 64 + mt * 16 + quad * 4;
        #pragma unroll
        for (int nt = 0; nt < 4; nt++) {
            int gn = n0 + cw * 64 + nt * 16 + l16;
            #pragma unroll
            for (int r = 0; r < 4; r++)
                out[(size_t)(gmBase + r) * 1024 + gn] = acc[mt][nt][r];
        }
    }
}

// ---------------- fused attention: S^T flash, 64 q-rows per wave ----------------
// grid: x = b*H+h (128), y = q-tile (4) -> XCD = bh%8: all q-tiles of a head share
// an XCD (K/V L2-resident). 512 blocks = 2/CU exactly. 4 waves x 64 q-rows.
// K-tiles of 64: per wave per tile 64 MFMA against 2 barriers + 16KB staging
// (2.7x better amortization than 32 q-rows). No max tracking (scores bounded).
__global__ __launch_bounds__(256) void attn_kernel(
        const u16* __restrict__ qb, const u16* __restrict__ kb,
        const u16* __restrict__ vb, const f32x4* __restrict__ F4,
        u16* __restrict__ ctx) {
    __shared__ u16 Kt[64 * 72];        // [kcol][dk]   9216 B
    __shared__ u16 Vt[64 * 72];        // [dk][scol]   9216 B
    __shared__ u16 Pt[4][64 * 40];     // per-wave P^T khalf buffer, stride 40  20480 B
    const int bh = blockIdx.x;
    const int h = bh & (NH - 1), b_ = bh >> 4;
    const int tid = threadIdx.x, w = tid >> 6, lane = tid & 63;
    const int quad = lane >> 4, l16 = lane & 15;
    const int q0 = blockIdx.y * 256 + w * 64;

    const f32x4* F4h = F4 + (size_t)h * 2047;

    // Q fragments (B-operand layout): bq[mt][c] = Q[q0+mt*16+l16][c*32+quad*8 ..+7]
    bf16x8 bq[4][2];
    #pragma unroll
    for (int mt = 0; mt < 4; mt++) {
        const u16* qrow = qb + ((size_t)bh * SEQ + q0 + mt * 16 + l16) * DK;
        bq[mt][0] = *(const bf16x8*)(qrow + quad * 8);
        bq[mt][1] = *(const bf16x8*)(qrow + 32 + quad * 8);
    }

    float l_[4] = {0.f, 0.f, 0.f, 0.f}; // lane-partial row sums (this quad's k only)
    f32x4 oacc[4][4];                   // O^T frags [mt][dt]
    #pragma unroll
    for (int mt = 0; mt < 4; mt++)
        #pragma unroll
        for (int dt = 0; dt < 4; dt++) oacc[mt][dt] = (f32x4){0.f, 0.f, 0.f, 0.f};

    const int srow = tid >> 3, sseg = tid & 7;   // staging: rows srow, srow+32

    const u16* kbase_p = kb + (size_t)bh * SEQ * DK;
    const u16* vbase_p = vb + (size_t)bh * DK * SEQ;

    // register prefetch of tile kt=0
    bf16x8 kr0 = *(const bf16x8*)&kbase_p[(size_t)srow * DK + sseg * 8];
    bf16x8 kr1 = *(const bf16x8*)&kbase_p[(size_t)(srow + 32) * DK + sseg * 8];
    bf16x8 vr0 = *(const bf16x8*)&vbase_p[(size_t)srow * SEQ + sseg * 8];
    bf16x8 vr1 = *(const bf16x8*)&vbase_p[(size_t)(srow + 32) * SEQ + sseg * 8];

    for (int kt = 0; kt < 16; kt++) {
        const int kbase = kt * 64;
        __syncthreads();               // prior-tile frag reads complete
        *(bf16x8*)&Kt[srow * 72 + sseg * 8] = kr0;
        *(bf16x8*)&Kt[(srow + 32) * 72 + sseg * 8] = kr1;
        *(bf16x8*)&Vt[srow * 72 + sseg * 8] = vr0;
        *(bf16x8*)&Vt[(srow + 32) * 72 + sseg * 8] = vr1;
        if (kt < 15) {                 // prefetch next tile (latency hidden by compute)
            const int nb = kbase + 64;
            kr0 = *(const bf16x8*)&kbase_p[(size_t)(nb + srow) * DK + sseg * 8];
            kr1 = *(const bf16x8*)&kbase_p[(size_t)(nb + srow + 32) * DK + sseg * 8];
            vr0 = *(const bf16x8*)&vbase_p[(size_t)srow * SEQ + nb + sseg * 8];
            vr1 = *(const bf16x8*)&vbase_p[(size_t)(srow + 32) * SEQ + nb + sseg * 8];
        }
        __syncthreads();               // staged tile visible

        // S^T = K·Q^T + bias (bias via accumulator init, log2 domain)
        f32x4 sc[4][4];
        #pragma unroll
        for (int mt = 0; mt < 4; mt++)
            #pragma unroll
            for (int nt = 0; nt < 4; nt++) {
                int t0 = (kbase + nt * 16 + quad * 4) - (q0 + mt * 16 + l16) + 1023;
                sc[mt][nt] = F4h[t0];
            }
        #pragma unroll
        for (int nt = 0; nt < 4; nt++) {
            bf16x8 ak0 = *(const bf16x8*)&Kt[(nt * 16 + l16) * 72 + quad * 8];
            bf16x8 ak1 = *(const bf16x8*)&Kt[(nt * 16 + l16) * 72 + 32 + quad * 8];
            #pragma unroll
            for (int mt = 0; mt < 4; mt++) {
                sc[mt][nt] = MFMA(ak0, bq[mt][0], sc[mt][nt]);
                sc[mt][nt] = MFMA(ak1, bq[mt][1], sc[mt][nt]);
            }
        }

        // exp2, pack P^T, PV — per k-half (wave-private Pt buffer, no extra barrier)
        #pragma unroll
        for (int c = 0; c < 2; c++) {
            #pragma unroll
            for (int mt = 0; mt < 4; mt++) {
                #pragma unroll
                for (int i = 0; i < 2; i++) {
                    int nt = 2 * c + i;
                    float p0 = exp2_raw(sc[mt][nt][0]);
                    float p1 = exp2_raw(sc[mt][nt][1]);
                    float p2 = exp2_raw(sc[mt][nt][2]);
                    float p3 = exp2_raw(sc[mt][nt][3]);
                    l_[mt] += (p0 + p1) + (p2 + p3);
                    bf16x4 pk;
                    pk[0] = (bf16)p0; pk[1] = (bf16)p1;
                    pk[2] = (bf16)p2; pk[3] = (bf16)p3;
                    *(bf16x4*)&Pt[w][(mt * 16 + l16) * 40 + i * 16 + quad * 4] = pk;
                }
            }
            // O^T += V^T · P^T for this k-half
            bf16x8 bp[4];
            #pragma unroll
            for (int mt = 0; mt < 4; mt++)
                bp[mt] = *(const bf16x8*)&Pt[w][(mt * 16 + l16) * 40 + quad * 8];
            #pragma unroll
            for (int dt = 0; dt < 4; dt++) {
                bf16x8 av = *(const bf16x8*)&Vt[(dt * 16 + l16) * 72 + c * 32 + quad * 8];
                #pragma unroll
                for (int mt = 0; mt < 4; mt++)
                    oacc[mt][dt] = MFMA(av, bp[mt], oacc[mt][dt]);
            }
        }
    }

    // epilogue: reduce l across quads (k-partials), normalize, write ctx
    #pragma unroll
    for (int mt = 0; mt < 4; mt++) {
        float l = l_[mt];
        l += __shfl_xor(l, 16, 64);
        l += __shfl_xor(l, 32, 64);
        float inv = 1.f / l;
        int gq = q0 + mt * 16 + l16;
        #pragma unroll
        for (int dt = 0; dt < 4; dt++) {
            u16x4 pk = { bfbits(oacc[mt][dt][0] * inv), bfbits(oacc[mt][dt][1] * inv),
                         bfbits(oacc[mt][dt][2] * inv), bfbits(oacc[mt][dt][3] * inv) };
            *(u16x4*)&ctx[((size_t)b_ * SEQ + gq) * DMODEL + h * DK + dt * 16 + quad * 4] = pk;
        }
    }
}

extern "C" void kernel_launch(void* const* d_in, const int* in_sizes, int n_in,
                              void* d_out, int out_size, void* d_ws, size_t ws_size,
                              hipStream_t stream) {
    const float* x   = (const float*)d_in[0];
    const float* Wq  = (const float*)d_in[1];
    const float* Wk  = (const float*)d_in[2];
    const float* Wv  = (const float*)d_in[3];
    const float* Wo  = (const float*)d_in[4];
    const float* rel = (const float*)d_in[5];
    float* out = (float*)d_out;

    char* p = (char*)d_ws;
    u16* xb  = (u16*)p; p += (size_t)BATCH * SEQ * DMODEL * 2;   // 16 MB
    u16* Wqt = (u16*)p; p += (size_t)DMODEL * DMODEL * 2;        // 2 MB each
    u16* Wkt = (u16*)p; p += (size_t)DMODEL * DMODEL * 2;
    u16* Wvt = (u16*)p; p += (size_t)DMODEL * DMODEL * 2;
    u16* Wot = (u16*)p; p += (size_t)DMODEL * DMODEL * 2;
    u16* qb  = (u16*)p; p += (size_t)BATCH * NH * SEQ * DK * 2;  // 16 MB each
    u16* kb  = (u16*)p; p += (size_t)BATCH * NH * SEQ * DK * 2;
    u16* vb  = (u16*)p; p += (size_t)BATCH * NH * SEQ * DK * 2;
    u16* ctx = (u16*)p; p += (size_t)BATCH * SEQ * DMODEL * 2;
    f32x4* F4 = (f32x4*)p; p += (size_t)NH * 2047 * 16;          // 0.5 MB

    // merged prep: converts + bias table in one launch
    prep_kernel<<<9344, 256, 0, stream>>>(x, Wq, Wk, Wv, Wo, rel,
                                          xb, Wqt, Wkt, Wvt, Wot, F4);

    // grid x = m0: per-XCD A-tile residency
    gemm_qkv_kernel<<<dim3(64, 24), 256, 0, stream>>>(xb, Wqt, Wkt, Wvt, qb, kb, vb);

    // 64 q-rows/wave, 512 blocks = 2/CU
    attn_kernel<<<dim3(128, 4), 256, 0, stream>>>(qb, kb, vb, F4, ctx);

    gemm_out_kernel<<<dim3(64, 8), 256, 0, stream>>>(ctx, Wot, out);
}